// Round 10
// baseline (814.600 us; speedup 1.0000x reference)
//
#include <hip/hip_runtime.h>
#include <hip/hip_bf16.h>
#include <stdint.h>

constexpr int L = 6, B = 16, S = 512, D = 512, SD = 128, E = 1536;

using bf16x8 = __attribute__((ext_vector_type(8))) short;
using f32x4  = __attribute__((ext_vector_type(4))) float;

typedef __attribute__((address_space(1))) void gvoid;
typedef __attribute__((address_space(3))) void lvoid;

__device__ __forceinline__ unsigned short f2bf(float f) {
    __hip_bfloat16 h = __float2bfloat16(f);
    return __builtin_bit_cast(unsigned short, h);
}
__device__ __forceinline__ float bf2f(unsigned short u) {
    unsigned int v = ((unsigned int)u) << 16;
    return __builtin_bit_cast(float, v);
}
__device__ __forceinline__ void gload16(const void* g, void* l) {
    __builtin_amdgcn_global_load_lds((gvoid*)g, (lvoid*)l, 16, 0, 0);
}

// bijective XCD-chunk swizzle (requires total blocks % 8 == 0).
__device__ __forceinline__ void swz_bid(int& bx, int& by, int& bz) {
    int gx = gridDim.x, gy = gridDim.y, gz = gridDim.z;
    int n = gx * gy * gz;
    int id = blockIdx.x + gx * (blockIdx.y + gy * blockIdx.z);
    int id2 = (id & 7) * (n >> 3) + (id >> 3);
    by = id2 % gy;
    int t = id2 / gy;
    bx = t % gx;
    bz = t / gx;
}

// ---------------- embedding + positional encoding (+ mask-layout detect, block 0) --
__global__ void embed_kernel(const int* __restrict__ tok, const float* __restrict__ embed,
                             float* __restrict__ x,
                             const unsigned char* __restrict__ m, int* flag) {
    if (blockIdx.x == 0) {
        if (threadIdx.x == 0) *flag = 0;
        __syncthreads();
        int any = 0;
        for (int i = threadIdx.x; i < B * S; i += blockDim.x)
            if ((i & 3) != 0 && m[i] != 0) any = 1;
        if (any) atomicOr(flag, 1);
    }
    int idx = blockIdx.x * blockDim.x + threadIdx.x;      // over B*S*D
    int d = idx & (D - 1);
    int bs = idx >> 9;                                    // D = 512 = 2^9
    int s = bs & (S - 1);
    float e = embed[(size_t)tok[bs] * D + d] * 22.62741699796952f;  // sqrt(512)
    float expo = (float)(d >> 1) * (1.0f / 256.0f);
    float ang = (float)s * expf(expo * -9.210340371976184f);
    float pe = (d & 1) ? cosf(ang) : sinf(ang);
    x[idx] = e + pe;
}

// ---- fused weight transpose+cast, all 4 weights, one launch. grid (2368, 1, L) ----
// tiles: [0,768) Wu 512x1536 | [768,1536) Wv | [1536,1600) Wz 512x128 | [1600,2368) Wo 1536x512
__global__ __launch_bounds__(256) void tcast_all(const float* __restrict__ Wu,
                                                 const float* __restrict__ Wv,
                                                 const float* __restrict__ Wz,
                                                 const float* __restrict__ Wo,
                                                 unsigned short* __restrict__ Wuvzt,
                                                 unsigned short* __restrict__ Wot) {
    constexpr long WUVZ = 3200L * 512;
    int l = blockIdx.z;
    int t = blockIdx.x;
    const float* src; unsigned short* dst; int K, N, r;
    if (t < 768)       { r = t;        src = Wu + (size_t)l * 512 * 1536; dst = Wuvzt + (size_t)l * WUVZ;               K = 512;  N = 1536; }
    else if (t < 1536) { r = t - 768;  src = Wv + (size_t)l * 512 * 1536; dst = Wuvzt + (size_t)l * WUVZ + 1536L * 512; K = 512;  N = 1536; }
    else if (t < 1600) { r = t - 1536; src = Wz + (size_t)l * 512 * 128;  dst = Wuvzt + (size_t)l * WUVZ + 3072L * 512; K = 512;  N = 128;  }
    else               { r = t - 1600; src = Wo + (size_t)l * 1536 * 512; dst = Wot + (size_t)l * 1536 * 512;           K = 1536; N = 512;  }
    int kx = K / 32;
    int k0 = (r % kx) * 32, n0 = (r / kx) * 32;
    __shared__ float tb[32][33];
    int tx = threadIdx.x & 31, ty = threadIdx.x >> 5;     // 32 x 8
#pragma unroll
    for (int i = 0; i < 4; ++i)
        tb[ty + i * 8][tx] = src[(size_t)(k0 + ty + i * 8) * N + n0 + tx];
    __syncthreads();
#pragma unroll
    for (int i = 0; i < 4; ++i)
        dst[(size_t)(n0 + ty + i * 8) * K + k0 + tx] = f2bf(tb[tx][ty + i * 8]);
}

// ---------------- layernorm: 4 rows/block, one wave per row of D=512 ----------------
template <bool BF>
__global__ __launch_bounds__(256) void ln_kernel(const float* __restrict__ x,
                                                 const float* __restrict__ g,
                                                 const float* __restrict__ b,
                                                 void* __restrict__ yp) {
    int row = blockIdx.x * 4 + (threadIdx.x >> 6);
    int lane = threadIdx.x & 63;
    const float* xr = x + (size_t)row * D;
    float4 v0 = *(const float4*)(xr + lane * 4);
    float4 v1 = *(const float4*)(xr + 256 + lane * 4);
    float sum = v0.x + v0.y + v0.z + v0.w + v1.x + v1.y + v1.z + v1.w;
#pragma unroll
    for (int o = 1; o < 64; o <<= 1) sum += __shfl_xor(sum, o);
    float m = sum * (1.0f / D);
    float d0 = v0.x - m, d1 = v0.y - m, d2 = v0.z - m, d3 = v0.w - m;
    float e0 = v1.x - m, e1 = v1.y - m, e2 = v1.z - m, e3 = v1.w - m;
    float sq = d0 * d0 + d1 * d1 + d2 * d2 + d3 * d3 + e0 * e0 + e1 * e1 + e2 * e2 + e3 * e3;
#pragma unroll
    for (int o = 1; o < 64; o <<= 1) sq += __shfl_xor(sq, o);
    float inv = rsqrtf(sq * (1.0f / D) + 1e-5f);
    int c0 = lane * 4, c1 = 256 + lane * 4;
    float4 g0 = *(const float4*)(g + c0), g1 = *(const float4*)(g + c1);
    float4 b0 = *(const float4*)(b + c0), b1 = *(const float4*)(b + c1);
    float o0 = d0 * inv * g0.x + b0.x, o1 = d1 * inv * g0.y + b0.y;
    float o2 = d2 * inv * g0.z + b0.z, o3 = d3 * inv * g0.w + b0.w;
    float o4 = e0 * inv * g1.x + b1.x, o5 = e1 * inv * g1.y + b1.y;
    float o6 = e2 * inv * g1.z + b1.z, o7 = e3 * inv * g1.w + b1.w;
    if constexpr (BF) {
        unsigned short* yr = (unsigned short*)yp + (size_t)row * D;
        ushort4 p0 = {f2bf(o0), f2bf(o1), f2bf(o2), f2bf(o3)};
        ushort4 p1 = {f2bf(o4), f2bf(o5), f2bf(o6), f2bf(o7)};
        *(ushort4*)(yr + c0) = p0;
        *(ushort4*)(yr + c1) = p1;
    } else {
        float* yr = (float*)yp + (size_t)row * D;
        float4 p0 = {o0, o1, o2, o3}, p1 = {o4, o5, o6, o7};
        *(float4*)(yr + c0) = p0;
        *(float4*)(yr + c1) = p1;
    }
}

// ---------------- MFMA GEMM core: tile BM x BN, BK=64, WM x WN waves --------------
// (R6 text — verified fastest codegen.) LDS [rows][64] bf16, chunk-XOR swizzle
// phys_chunk = log_chunk ^ (row&7). Staging via global_load_lds(16B), pre-swizzled
// per-lane global source. SWAP=true: mfma(bF,aF) -> lane regs walk N => coalesced C.
template <int BM, int BN, int WM, int WN, bool SWAP>
__device__ __forceinline__ void gemm_core(const unsigned short* __restrict__ Ab,
                                          const unsigned short* __restrict__ Bb,
                                          int K, short* lsA, short* lsB,
                                          f32x4 (&acc)[BM / WM / 16][BN / WN / 16],
                                          int lane, int wv) {
    constexpr int NW = WM * WN;
    constexpr int NA = BM / 8 / NW, NB = BN / 8 / NW;   // 1KB segs per wave
    constexpr int WTM = BM / WM, WTN = BN / WN;
    constexpr int FM = WTM / 16, FN = WTN / 16;
    const int wm = wv / WN, wn = wv % WN;
    const unsigned short* ga[NA]; int lofsA[NA];
    const unsigned short* gb[NB]; int lofsB[NB];
#pragma unroll
    for (int i = 0; i < NA; ++i) {
        int s = wv * NA + i;
        int r = s * 8 + (lane >> 3);
        int cl = (lane & 7) ^ (r & 7);
        ga[i] = Ab + (size_t)r * K + cl * 8;
        lofsA[i] = s * 512;
    }
#pragma unroll
    for (int i = 0; i < NB; ++i) {
        int s = wv * NB + i;
        int r = s * 8 + (lane >> 3);
        int cl = (lane & 7) ^ (r & 7);
        gb[i] = Bb + (size_t)r * K + cl * 8;
        lofsB[i] = s * 512;
    }
    const int nkt = K >> 6;
    for (int kt = 0; kt < nkt; ++kt) {
        if (kt) __syncthreads();
#pragma unroll
        for (int i = 0; i < NA; ++i) gload16(ga[i] + kt * 64, (void*)&lsA[lofsA[i]]);
#pragma unroll
        for (int i = 0; i < NB; ++i) gload16(gb[i] + kt * 64, (void*)&lsB[lofsB[i]]);
        __syncthreads();
#pragma unroll
        for (int ks = 0; ks < 2; ++ks) {
            bf16x8 aF[FM], bF[FN];
#pragma unroll
            for (int f = 0; f < FM; ++f) {
                int ra = wm * WTM + f * 16 + (lane & 15);
                int ca = (ks * 4 + (lane >> 4)) ^ (ra & 7);
                aF[f] = *(const bf16x8*)&lsA[ra * 64 + ca * 8];
            }
#pragma unroll
            for (int f = 0; f < FN; ++f) {
                int rb = wn * WTN + f * 16 + (lane & 15);
                int cb = (ks * 4 + (lane >> 4)) ^ (rb & 7);
                bF[f] = *(const bf16x8*)&lsB[rb * 64 + cb * 8];
            }
#pragma unroll
            for (int fi = 0; fi < FM; ++fi)
#pragma unroll
                for (int fj = 0; fj < FN; ++fj) {
                    if constexpr (SWAP)
                        acc[fi][fj] = __builtin_amdgcn_mfma_f32_16x16x32_bf16(
                            bF[fj], aF[fi], acc[fi][fj], 0, 0, 0);
                    else
                        acc[fi][fj] = __builtin_amdgcn_mfma_f32_16x16x32_bf16(
                            aF[fi], bF[fj], acc[fi][fj], 0, 0, 0);
                }
        }
    }
}

// -------- fused u|v|z+qk GEMM over xn(8192x512), 128^2 tiles, flat grid (1600) -----
// t<768: u (SWAP, bias->bf16 row-major); t<1536: v^T (NOSWAP, [b][c][t]);
// t>=1536: z+qk (SWAP): q=z*gq+bq, k=z*gk+bk, bf16, 64 row-blocks x 1 col-block.
__global__ __launch_bounds__(256) void uvz_gemm(const unsigned short* __restrict__ xn,
                                                const unsigned short* __restrict__ Wt,
                                                const float* __restrict__ bu,
                                                const float* __restrict__ bvp,
                                                const float* __restrict__ bzp,
                                                const float* __restrict__ gq,
                                                const float* __restrict__ bq,
                                                const float* __restrict__ gk,
                                                const float* __restrict__ bk,
                                                unsigned short* __restrict__ u,
                                                unsigned short* __restrict__ vt,
                                                unsigned short* __restrict__ q,
                                                unsigned short* __restrict__ k) {
    __shared__ short lsA[128 * 64];
    __shared__ short lsB[128 * 64];
    int t, dum1, dum2;
    swz_bid(t, dum1, dum2);
    const int tid = threadIdx.x;
    const int lane = tid & 63, wv = tid >> 6;
    const int wm = wv >> 1, wn = wv & 1;
    const int lr4 = (lane >> 4) * 4;
    const int lc = lane & 15;

    if (t < 768) {                       // ---- u region (SWAP) ----
        int bx = t & 63, by = t >> 6;
        int row0 = bx * 128, col0 = by * 128;
        const unsigned short* Ab = xn + (size_t)row0 * D;
        const unsigned short* Bb = Wt + (size_t)col0 * D;
        f32x4 acc[4][4] = {};
        gemm_core<128, 128, 2, 2, true>(Ab, Bb, D, lsA, lsB, acc, lane, wv);
#pragma unroll
        for (int fi = 0; fi < 4; ++fi) {
            int r = row0 + wm * 64 + fi * 16 + lc;
#pragma unroll
            for (int fj = 0; fj < 4; ++fj) {
                int cb = col0 + wn * 64 + fj * 16 + lr4;
                f32x4 v = acc[fi][fj];
                f32x4 bv = *(const f32x4*)&bu[cb];
                ushort4 ov = {f2bf(v[0] + bv[0]), f2bf(v[1] + bv[1]),
                              f2bf(v[2] + bv[2]), f2bf(v[3] + bv[3])};
                *(ushort4*)&u[(size_t)r * E + cb] = ov;
            }
        }
    } else if (t < 1536) {               // ---- v^T region (NOSWAP) ----
        int tt = t - 768;
        int bx = tt & 63, by = tt >> 6;
        int row0 = bx * 128, col0 = by * 128;
        const unsigned short* Ab = xn + (size_t)row0 * D;
        const unsigned short* Bb = Wt + (size_t)(1536 + col0) * D;
        f32x4 acc[4][4] = {};
        gemm_core<128, 128, 2, 2, false>(Ab, Bb, D, lsA, lsB, acc, lane, wv);
#pragma unroll
        for (int fi = 0; fi < 4; ++fi) {
            int rb = row0 + wm * 64 + fi * 16 + lr4;
            int b = rb >> 9, t0 = rb & 511;
#pragma unroll
            for (int fj = 0; fj < 4; ++fj) {
                int c = col0 + wn * 64 + fj * 16 + lc;
                f32x4 v = acc[fi][fj];
                float bv = bvp[c];
                ushort4 ov = {f2bf(v[0] + bv), f2bf(v[1] + bv),
                              f2bf(v[2] + bv), f2bf(v[3] + bv)};
                *(ushort4*)&vt[((size_t)b * E + c) * 512 + t0] = ov;
            }
        }
    } else {                             // ---- z region -> q,k fused (SWAP) ----
        int bx = t - 1536;
        int row0 = bx * 128;
        const unsigned short* Ab = xn + (size_t)row0 * D;
        const unsigned short* Bb = Wt + (size_t)3072 * D;
        f32x4 acc[4][4] = {};
        gemm_core<128, 128, 2, 2, true>(Ab, Bb, D, lsA, lsB, acc, lane, wv);
#pragma unroll
        for (int fi = 0; fi < 4; ++fi) {
            int r = row0 + wm * 64 + fi * 16 + lc;
            int s = r & 511;
#pragma unroll
            for (int fj = 0; fj < 4; ++fj) {
                int cb = wn * 64 + fj * 16 + lr4;    // [0,128)
                f32x4 v = acc[fi][fj];
                f32x4 bz4 = *(const f32x4*)&bzp[cb];
                f32x4 gq4 = *(const f32x4*)&gq[(size_t)s * SD + cb];
                f32x4 bq4 = *(const f32x4*)&bq[(size_t)s * SD + cb];
                f32x4 gk4 = *(const f32x4*)&gk[(size_t)s * SD + cb];
                f32x4 bk4 = *(const f32x4*)&bk[(size_t)s * SD + cb];
                ushort4 qv, kv;
#pragma unroll
                for (int g = 0; g < 4; ++g) {
                    float zz = v[g] + bz4[g];
                    ((unsigned short*)&qv)[g] = f2bf(fmaf(zz, gq4[g], bq4[g]));
                    ((unsigned short*)&kv)[g] = f2bf(fmaf(zz, gk4[g], bk4[g]));
                }
                *(ushort4*)&q[(size_t)r * SD + cb] = qv;
                *(ushort4*)&k[(size_t)r * SD + cb] = kv;
            }
        }
    }
}

// ---- scores: a = relu^2(q@k^T) masked, BM=128 BN=64, K=128 fully prefetched -------
// Both K-tiles staged into separate buffers up front -> ONE barrier, no buffer reuse.
// grid (4, 8, B). LDS 48KB -> 3 blocks/CU >= grid 2/CU (no occupancy loss).
__global__ __launch_bounds__(256) void score_gemm(const unsigned short* __restrict__ q,
                                                  const unsigned short* __restrict__ km,
                                                  const unsigned char* __restrict__ maskb,
                                                  const int* __restrict__ flagp,
                                                  unsigned short* __restrict__ a) {
    __shared__ short lsA[2][128 * 64];
    __shared__ short lsB[2][64 * 64];
    int bx, by, bz;
    swz_bid(bx, by, bz);
    const int tid = threadIdx.x;
    const int lane = tid & 63, wv = tid >> 6;
    const int wm = wv >> 1, wn = wv & 1;     // 2x2 waves, wave tile 64x32
    const int row0 = bx * 128, col0 = by * 64;
    const unsigned short* Ab = q + (size_t)bz * S * SD + (size_t)row0 * SD;
    const unsigned short* Bb = km + (size_t)bz * S * SD + (size_t)col0 * SD;

    const unsigned short* ga[4]; int lofsA[4];
    const unsigned short* gb[2]; int lofsB[2];
#pragma unroll
    for (int i = 0; i < 4; ++i) {
        int s = wv * 4 + i;
        int r = s * 8 + (lane >> 3);
        int cl = (lane & 7) ^ (r & 7);
        ga[i] = Ab + (size_t)r * SD + cl * 8;
        lofsA[i] = s * 512;
    }
#pragma unroll
    for (int i = 0; i < 2; ++i) {
        int s = wv * 2 + i;
        int r = s * 8 + (lane >> 3);
        int cl = (lane & 7) ^ (r & 7);
        gb[i] = Bb + (size_t)r * SD + cl * 8;
        lofsB[i] = s * 512;
    }
    // stage both K-tiles (kt=0,1) into independent buffers, single barrier
#pragma unroll
    for (int i = 0; i < 4; ++i) gload16(ga[i], (void*)&lsA[0][lofsA[i]]);
#pragma unroll
    for (int i = 0; i < 2; ++i) gload16(gb[i], (void*)&lsB[0][lofsB[i]]);
#pragma unroll
    for (int i = 0; i < 4; ++i) gload16(ga[i] + 64, (void*)&lsA[1][lofsA[i]]);
#pragma unroll
    for (int i = 0; i < 2; ++i) gload16(gb[i] + 64, (void*)&lsB[1][lofsB[i]]);
    __syncthreads();

    f32x4 acc[4][2] = {};
#pragma unroll
    for (int kt = 0; kt < 2; ++kt) {
#pragma unroll
        for (int ks = 0; ks < 2; ++ks) {
            bf16x8 aF[4], bF[2];
#pragma unroll
            for (int f = 0; f < 4; ++f) {
                int ra = wm * 64 + f * 16 + (lane & 15);
                int ca = (ks * 4 + (lane >> 4)) ^ (ra & 7);
                aF[f] = *(const bf16x8*)&lsA[kt][ra * 64 + ca * 8];
            }
#pragma unroll
            for (int f = 0; f < 2; ++f) {
                int rb = wn * 32 + f * 16 + (lane & 15);
                int cb = (ks * 4 + (lane >> 4)) ^ (rb & 7);
                bF[f] = *(const bf16x8*)&lsB[kt][rb * 64 + cb * 8];
            }
#pragma unroll
            for (int fi = 0; fi < 4; ++fi)
#pragma unroll
                for (int fj = 0; fj < 2; ++fj)
                    acc[fi][fj] = __builtin_amdgcn_mfma_f32_16x16x32_bf16(
                        bF[fj], aF[fi], acc[fi][fj], 0, 0, 0);   // SWAP layout
        }
    }

    const int lr4 = (lane >> 4) * 4;
    const int lc = lane & 15;
    unsigned short* C = a + (size_t)bz * S * S;
    int flag = *flagp;
#pragma unroll
    for (int fi = 0; fi < 4; ++fi) {
        int r = row0 + wm * 64 + fi * 16 + lc;
#pragma unroll
        for (int fj = 0; fj < 2; ++fj) {
            int cb = col0 + wn * 32 + fj * 16 + lr4;
            f32x4 v = acc[fi][fj];
            ushort4 ov;
#pragma unroll
            for (int g = 0; g < 4; ++g) {
                int c = cb + g;
                int mv = flag ? (int)maskb[bz * S + c] : ((const int*)maskb)[bz * S + c];
                float vv = fmaxf(v[g], 0.0f);
                vv *= vv;
                ((unsigned short*)&ov)[g] = mv ? (unsigned short)0 : f2bf(vv);
            }
            *(ushort4*)&C[(size_t)r * S + cb] = ov;
        }
    }
}

// EPI: 4 u*acc->bf16 | 5 bias+residual->f32   (SWAP layout)
template <int EPI, int BM, int BN, int WM, int WN>
__global__ __launch_bounds__(256) void mgemm(const unsigned short* __restrict__ A,
                                             const unsigned short* __restrict__ Bt,
                                             const float* __restrict__ bias,
                                             const void* __restrict__ aux,
                                             const int* __restrict__ flagp,
                                             void* __restrict__ Cp,
                                             int N, int K,
                                             long sA, long sB, long sC, long sAux) {
    __shared__ short lsA[BM * 64];
    __shared__ short lsB[BN * 64];
    constexpr int FM = BM / WM / 16, FN = BN / WN / 16;
    int bx, by, bz;
    swz_bid(bx, by, bz);
    const int tid = threadIdx.x;
    const int lane = tid & 63, wv = tid >> 6;
    const int wm = wv / WN, wn = wv % WN;
    const int row0 = bx * BM, col0 = by * BN;

    const unsigned short* Ab = A + (size_t)bz * sA + (size_t)row0 * K;
    const unsigned short* Bb = Bt + (size_t)bz * sB + (size_t)col0 * K;

    f32x4 acc[FM][FN] = {};
    gemm_core<BM, BN, WM, WN, true>(Ab, Bb, K, lsA, lsB, acc, lane, wv);

    const int lr4 = (lane >> 4) * 4;
    const int lc = lane & 15;
#pragma unroll
    for (int fi = 0; fi < FM; ++fi) {
        int r = row0 + wm * (BM / WM) + fi * 16 + lc;
#pragma unroll
        for (int fj = 0; fj < FN; ++fj) {
            int cb = col0 + wn * (BN / WN) + fj * 16 + lr4;
            f32x4 v = acc[fi][fj];
            if constexpr (EPI == 4) {          // o = u * (a@v)
                const unsigned short* U = (const unsigned short*)aux + (size_t)bz * sAux;
                unsigned short* C = (unsigned short*)Cp + (size_t)bz * sC;
                size_t off = (size_t)r * N + cb;
                ushort4 uu = *(const ushort4*)&U[off];
                ushort4 ov = {f2bf(bf2f(uu.x) * v[0]), f2bf(bf2f(uu.y) * v[1]),
                              f2bf(bf2f(uu.z) * v[2]), f2bf(bf2f(uu.w) * v[3])};
                *(ushort4*)&C[off] = ov;
            } else {                           // EPI 5: bias + residual, f32 in-place
                float* C = (float*)Cp;
                const float* X = (const float*)aux;
                size_t off = (size_t)r * N + cb;
                f32x4 bb = *(const f32x4*)&bias[cb];
                f32x4 xx = *(const f32x4*)&X[off];
                f32x4 ov = {v[0] + bb[0] + xx[0], v[1] + bb[1] + xx[1],
                            v[2] + bb[2] + xx[2], v[3] + bb[3] + xx[3]};
                *(f32x4*)&C[off] = ov;
            }
        }
    }
}

extern "C" void kernel_launch(void* const* d_in, const int* in_sizes, int n_in,
                              void* d_out, int out_size, void* d_ws, size_t ws_size,
                              hipStream_t stream) {
    const int* tok = (const int*)d_in[0];
    const unsigned char* mask = (const unsigned char*)d_in[1];
    const float* embed = (const float*)d_in[2];
    const float* ln_g = (const float*)d_in[3];
    const float* ln_b = (const float*)d_in[4];
    const float* Wz = (const float*)d_in[5];
    const float* bz = (const float*)d_in[6];
    const float* gq = (const float*)d_in[7];
    const float* bq = (const float*)d_in[8];
    const float* gk = (const float*)d_in[9];
    const float* bk = (const float*)d_in[10];
    const float* Wu = (const float*)d_in[11];
    const float* bu = (const float*)d_in[12];
    const float* Wv = (const float*)d_in[13];
    const float* bv = (const float*)d_in[14];
    const float* Wo = (const float*)d_in[15];
    const float* bo = (const float*)d_in[16];
    const float* fin_g = (const float*)d_in[17];
    const float* fin_b = (const float*)d_in[18];

    char* wsb = (char*)d_ws;
    size_t off = 0;
    auto alloc = [&](size_t nbytes) {
        void* p = wsb + off;
        off = (off + nbytes + 255) & ~(size_t)255;
        return p;
    };
    int* flag = (int*)alloc(256);
    float* x = (float*)alloc((size_t)B * S * D * 4);
    unsigned short* xn = (unsigned short*)alloc((size_t)B * S * D * 2);
    unsigned short* q = (unsigned short*)alloc((size_t)B * S * SD * 2);
    unsigned short* k = (unsigned short*)alloc((size_t)B * S * SD * 2);
    unsigned short* u = (unsigned short*)alloc((size_t)B * S * E * 2);
    unsigned short* vt = (unsigned short*)alloc((size_t)B * E * S * 2);
    unsigned short* o = (unsigned short*)alloc((size_t)B * S * E * 2);
    unsigned short* a = (unsigned short*)alloc((size_t)B * S * S * 2);
    unsigned short* Wuvzt = (unsigned short*)alloc((size_t)L * 3200 * D * 2);
    unsigned short* Wot = (unsigned short*)alloc((size_t)L * D * E * 2);

    constexpr long WUVZ = 3200L * D;   // per-layer stride of concat weight [u|v|z]

    embed_kernel<<<(B * S * D) / 256, 256, 0, stream>>>(tok, embed, x, mask, flag);
    tcast_all<<<dim3(2368, 1, L), 256, 0, stream>>>(Wu, Wv, Wz, Wo, Wuvzt, Wot);

    for (int l = 0; l < L; ++l) {
        ln_kernel<true><<<B * S / 4, 256, 0, stream>>>(x, ln_g + l * D, ln_b + l * D, xn);
        uvz_gemm<<<dim3(1600), 256, 0, stream>>>(
            xn, Wuvzt + (size_t)l * WUVZ, bu + l * E, bv + l * E, bz + l * SD,
            gq + (size_t)l * S * SD, bq + (size_t)l * S * SD,
            gk + (size_t)l * S * SD, bk + (size_t)l * S * SD, u, vt, q, k);
        score_gemm<<<dim3(4, 8, B), 256, 0, stream>>>(q, k, mask, flag, a);
        mgemm<4, 128, 128, 2, 2><<<dim3(4, 12, B), 256, 0, stream>>>(
            a, vt, nullptr, u, nullptr, o, E, S,
            (long)S * S, (long)E * S, (long)S * E, (long)S * E);
        mgemm<5, 128, 64, 2, 2><<<dim3(64, 8), 256, 0, stream>>>(
            o, Wot + (size_t)l * D * E, bo + l * D, x, nullptr, x, D, E, 0, 0, 0, 0);
    }
    ln_kernel<false><<<B * S / 4, 256, 0, stream>>>(x, fin_g, fin_b, (float*)d_out);
}

// Round 11
// 792.853 us; speedup vs baseline: 1.0274x; 1.0274x over previous
//
#include <hip/hip_runtime.h>
#include <hip/hip_bf16.h>
#include <stdint.h>

constexpr int L = 6, B = 16, S = 512, D = 512, SD = 128, E = 1536;

using bf16x8 = __attribute__((ext_vector_type(8))) short;
using f32x4  = __attribute__((ext_vector_type(4))) float;

typedef __attribute__((address_space(1))) void gvoid;
typedef __attribute__((address_space(3))) void lvoid;

__device__ __forceinline__ unsigned short f2bf(float f) {
    __hip_bfloat16 h = __float2bfloat16(f);
    return __builtin_bit_cast(unsigned short, h);
}
__device__ __forceinline__ float bf2f(unsigned short u) {
    unsigned int v = ((unsigned int)u) << 16;
    return __builtin_bit_cast(float, v);
}
__device__ __forceinline__ void gload16(const void* g, void* l) {
    __builtin_amdgcn_global_load_lds((gvoid*)g, (lvoid*)l, 16, 0, 0);
}

// bijective XCD-chunk swizzle (requires total blocks % 8 == 0).
__device__ __forceinline__ void swz_bid(int& bx, int& by, int& bz) {
    int gx = gridDim.x, gy = gridDim.y, gz = gridDim.z;
    int n = gx * gy * gz;
    int id = blockIdx.x + gx * (blockIdx.y + gy * blockIdx.z);
    int id2 = (id & 7) * (n >> 3) + (id >> 3);
    by = id2 % gy;
    int t = id2 / gy;
    bx = t % gx;
    bz = t / gx;
}

// ---------------- embedding + positional encoding (+ mask-layout detect, block 0) --
__global__ void embed_kernel(const int* __restrict__ tok, const float* __restrict__ embed,
                             float* __restrict__ x,
                             const unsigned char* __restrict__ m, int* flag) {
    if (blockIdx.x == 0) {
        if (threadIdx.x == 0) *flag = 0;
        __syncthreads();
        int any = 0;
        for (int i = threadIdx.x; i < B * S; i += blockDim.x)
            if ((i & 3) != 0 && m[i] != 0) any = 1;
        if (any) atomicOr(flag, 1);
    }
    int idx = blockIdx.x * blockDim.x + threadIdx.x;      // over B*S*D
    int d = idx & (D - 1);
    int bs = idx >> 9;                                    // D = 512 = 2^9
    int s = bs & (S - 1);
    float e = embed[(size_t)tok[bs] * D + d] * 22.62741699796952f;  // sqrt(512)
    float expo = (float)(d >> 1) * (1.0f / 256.0f);
    float ang = (float)s * expf(expo * -9.210340371976184f);
    float pe = (d & 1) ? cosf(ang) : sinf(ang);
    x[idx] = e + pe;
}

// ---- fused weight transpose+cast, all 4 weights, one launch. grid (2368, 1, L) ----
// tiles: [0,768) Wu 512x1536 | [768,1536) Wv | [1536,1600) Wz 512x128 | [1600,2368) Wo 1536x512
__global__ __launch_bounds__(256) void tcast_all(const float* __restrict__ Wu,
                                                 const float* __restrict__ Wv,
                                                 const float* __restrict__ Wz,
                                                 const float* __restrict__ Wo,
                                                 unsigned short* __restrict__ Wuvzt,
                                                 unsigned short* __restrict__ Wot) {
    constexpr long WUVZ = 3200L * 512;
    int l = blockIdx.z;
    int t = blockIdx.x;
    const float* src; unsigned short* dst; int K, N, r;
    if (t < 768)       { r = t;        src = Wu + (size_t)l * 512 * 1536; dst = Wuvzt + (size_t)l * WUVZ;               K = 512;  N = 1536; }
    else if (t < 1536) { r = t - 768;  src = Wv + (size_t)l * 512 * 1536; dst = Wuvzt + (size_t)l * WUVZ + 1536L * 512; K = 512;  N = 1536; }
    else if (t < 1600) { r = t - 1536; src = Wz + (size_t)l * 512 * 128;  dst = Wuvzt + (size_t)l * WUVZ + 3072L * 512; K = 512;  N = 128;  }
    else               { r = t - 1600; src = Wo + (size_t)l * 1536 * 512; dst = Wot + (size_t)l * 1536 * 512;           K = 1536; N = 512;  }
    int kx = K / 32;
    int k0 = (r % kx) * 32, n0 = (r / kx) * 32;
    __shared__ float tb[32][33];
    int tx = threadIdx.x & 31, ty = threadIdx.x >> 5;     // 32 x 8
#pragma unroll
    for (int i = 0; i < 4; ++i)
        tb[ty + i * 8][tx] = src[(size_t)(k0 + ty + i * 8) * N + n0 + tx];
    __syncthreads();
#pragma unroll
    for (int i = 0; i < 4; ++i)
        dst[(size_t)(n0 + ty + i * 8) * K + k0 + tx] = f2bf(tb[tx][ty + i * 8]);
}

// ---------------- layernorm: 4 rows/block, one wave per row of D=512 ----------------
template <bool BF>
__global__ __launch_bounds__(256) void ln_kernel(const float* __restrict__ x,
                                                 const float* __restrict__ g,
                                                 const float* __restrict__ b,
                                                 void* __restrict__ yp) {
    int row = blockIdx.x * 4 + (threadIdx.x >> 6);
    int lane = threadIdx.x & 63;
    const float* xr = x + (size_t)row * D;
    float4 v0 = *(const float4*)(xr + lane * 4);
    float4 v1 = *(const float4*)(xr + 256 + lane * 4);
    float sum = v0.x + v0.y + v0.z + v0.w + v1.x + v1.y + v1.z + v1.w;
#pragma unroll
    for (int o = 1; o < 64; o <<= 1) sum += __shfl_xor(sum, o);
    float m = sum * (1.0f / D);
    float d0 = v0.x - m, d1 = v0.y - m, d2 = v0.z - m, d3 = v0.w - m;
    float e0 = v1.x - m, e1 = v1.y - m, e2 = v1.z - m, e3 = v1.w - m;
    float sq = d0 * d0 + d1 * d1 + d2 * d2 + d3 * d3 + e0 * e0 + e1 * e1 + e2 * e2 + e3 * e3;
#pragma unroll
    for (int o = 1; o < 64; o <<= 1) sq += __shfl_xor(sq, o);
    float inv = rsqrtf(sq * (1.0f / D) + 1e-5f);
    int c0 = lane * 4, c1 = 256 + lane * 4;
    float4 g0 = *(const float4*)(g + c0), g1 = *(const float4*)(g + c1);
    float4 b0 = *(const float4*)(b + c0), b1 = *(const float4*)(b + c1);
    float o0 = d0 * inv * g0.x + b0.x, o1 = d1 * inv * g0.y + b0.y;
    float o2 = d2 * inv * g0.z + b0.z, o3 = d3 * inv * g0.w + b0.w;
    float o4 = e0 * inv * g1.x + b1.x, o5 = e1 * inv * g1.y + b1.y;
    float o6 = e2 * inv * g1.z + b1.z, o7 = e3 * inv * g1.w + b1.w;
    if constexpr (BF) {
        unsigned short* yr = (unsigned short*)yp + (size_t)row * D;
        ushort4 p0 = {f2bf(o0), f2bf(o1), f2bf(o2), f2bf(o3)};
        ushort4 p1 = {f2bf(o4), f2bf(o5), f2bf(o6), f2bf(o7)};
        *(ushort4*)(yr + c0) = p0;
        *(ushort4*)(yr + c1) = p1;
    } else {
        float* yr = (float*)yp + (size_t)row * D;
        float4 p0 = {o0, o1, o2, o3}, p1 = {o4, o5, o6, o7};
        *(float4*)(yr + c0) = p0;
        *(float4*)(yr + c1) = p1;
    }
}

// ---------------- MFMA GEMM core: tile BM x BN, BK=64, WM x WN waves --------------
// (R6 text — verified fastest codegen.) LDS [rows][64] bf16, chunk-XOR swizzle
// phys_chunk = log_chunk ^ (row&7). Staging via global_load_lds(16B), pre-swizzled
// per-lane global source. SWAP=true: mfma(bF,aF) -> lane regs walk N => coalesced C.
template <int BM, int BN, int WM, int WN, bool SWAP>
__device__ __forceinline__ void gemm_core(const unsigned short* __restrict__ Ab,
                                          const unsigned short* __restrict__ Bb,
                                          int K, short* lsA, short* lsB,
                                          f32x4 (&acc)[BM / WM / 16][BN / WN / 16],
                                          int lane, int wv) {
    constexpr int NW = WM * WN;
    constexpr int NA = BM / 8 / NW, NB = BN / 8 / NW;   // 1KB segs per wave
    constexpr int WTM = BM / WM, WTN = BN / WN;
    constexpr int FM = WTM / 16, FN = WTN / 16;
    const int wm = wv / WN, wn = wv % WN;
    const unsigned short* ga[NA]; int lofsA[NA];
    const unsigned short* gb[NB]; int lofsB[NB];
#pragma unroll
    for (int i = 0; i < NA; ++i) {
        int s = wv * NA + i;
        int r = s * 8 + (lane >> 3);
        int cl = (lane & 7) ^ (r & 7);
        ga[i] = Ab + (size_t)r * K + cl * 8;
        lofsA[i] = s * 512;
    }
#pragma unroll
    for (int i = 0; i < NB; ++i) {
        int s = wv * NB + i;
        int r = s * 8 + (lane >> 3);
        int cl = (lane & 7) ^ (r & 7);
        gb[i] = Bb + (size_t)r * K + cl * 8;
        lofsB[i] = s * 512;
    }
    const int nkt = K >> 6;
    for (int kt = 0; kt < nkt; ++kt) {
        if (kt) __syncthreads();
#pragma unroll
        for (int i = 0; i < NA; ++i) gload16(ga[i] + kt * 64, (void*)&lsA[lofsA[i]]);
#pragma unroll
        for (int i = 0; i < NB; ++i) gload16(gb[i] + kt * 64, (void*)&lsB[lofsB[i]]);
        __syncthreads();
#pragma unroll
        for (int ks = 0; ks < 2; ++ks) {
            bf16x8 aF[FM], bF[FN];
#pragma unroll
            for (int f = 0; f < FM; ++f) {
                int ra = wm * WTM + f * 16 + (lane & 15);
                int ca = (ks * 4 + (lane >> 4)) ^ (ra & 7);
                aF[f] = *(const bf16x8*)&lsA[ra * 64 + ca * 8];
            }
#pragma unroll
            for (int f = 0; f < FN; ++f) {
                int rb = wn * WTN + f * 16 + (lane & 15);
                int cb = (ks * 4 + (lane >> 4)) ^ (rb & 7);
                bF[f] = *(const bf16x8*)&lsB[rb * 64 + cb * 8];
            }
#pragma unroll
            for (int fi = 0; fi < FM; ++fi)
#pragma unroll
                for (int fj = 0; fj < FN; ++fj) {
                    if constexpr (SWAP)
                        acc[fi][fj] = __builtin_amdgcn_mfma_f32_16x16x32_bf16(
                            bF[fj], aF[fi], acc[fi][fj], 0, 0, 0);
                    else
                        acc[fi][fj] = __builtin_amdgcn_mfma_f32_16x16x32_bf16(
                            aF[fi], bF[fj], acc[fi][fj], 0, 0, 0);
                }
        }
    }
}

// -------- fused u|v|z+qk GEMM over xn(8192x512), 128^2 tiles, flat grid (1600) -----
// Region decode is COL-FASTEST (by = t % 12) so each XCD's contiguous swizzle chunk
// covers all weight columns x ~16 xn row-blocks -> xn L2-resident per XCD (R10 bug:
// row-fastest decode made every XCD stream all of xn, FETCH 86 MB vs 20).
// t<768: u (SWAP); t<1536: v^T (NOSWAP, [b][c][t]); t>=1536: z+qk (SWAP).
__global__ __launch_bounds__(256) void uvz_gemm(const unsigned short* __restrict__ xn,
                                                const unsigned short* __restrict__ Wt,
                                                const float* __restrict__ bu,
                                                const float* __restrict__ bvp,
                                                const float* __restrict__ bzp,
                                                const float* __restrict__ gq,
                                                const float* __restrict__ bq,
                                                const float* __restrict__ gk,
                                                const float* __restrict__ bk,
                                                unsigned short* __restrict__ u,
                                                unsigned short* __restrict__ vt,
                                                unsigned short* __restrict__ q,
                                                unsigned short* __restrict__ k) {
    __shared__ short lsA[128 * 64];
    __shared__ short lsB[128 * 64];
    int t, dum1, dum2;
    swz_bid(t, dum1, dum2);
    const int tid = threadIdx.x;
    const int lane = tid & 63, wv = tid >> 6;
    const int wm = wv >> 1, wn = wv & 1;
    const int lr4 = (lane >> 4) * 4;
    const int lc = lane & 15;

    if (t < 768) {                       // ---- u region (SWAP), col-fastest ----
        int by = t % 12, bx = t / 12;
        int row0 = bx * 128, col0 = by * 128;
        const unsigned short* Ab = xn + (size_t)row0 * D;
        const unsigned short* Bb = Wt + (size_t)col0 * D;
        f32x4 acc[4][4] = {};
        gemm_core<128, 128, 2, 2, true>(Ab, Bb, D, lsA, lsB, acc, lane, wv);
#pragma unroll
        for (int fi = 0; fi < 4; ++fi) {
            int r = row0 + wm * 64 + fi * 16 + lc;
#pragma unroll
            for (int fj = 0; fj < 4; ++fj) {
                int cb = col0 + wn * 64 + fj * 16 + lr4;
                f32x4 v = acc[fi][fj];
                f32x4 bv = *(const f32x4*)&bu[cb];
                ushort4 ov = {f2bf(v[0] + bv[0]), f2bf(v[1] + bv[1]),
                              f2bf(v[2] + bv[2]), f2bf(v[3] + bv[3])};
                *(ushort4*)&u[(size_t)r * E + cb] = ov;
            }
        }
    } else if (t < 1536) {               // ---- v^T region (NOSWAP), col-fastest ----
        int tt = t - 768;
        int by = tt % 12, bx = tt / 12;
        int row0 = bx * 128, col0 = by * 128;
        const unsigned short* Ab = xn + (size_t)row0 * D;
        const unsigned short* Bb = Wt + (size_t)(1536 + col0) * D;
        f32x4 acc[4][4] = {};
        gemm_core<128, 128, 2, 2, false>(Ab, Bb, D, lsA, lsB, acc, lane, wv);
#pragma unroll
        for (int fi = 0; fi < 4; ++fi) {
            int rb = row0 + wm * 64 + fi * 16 + lr4;
            int b = rb >> 9, t0 = rb & 511;
#pragma unroll
            for (int fj = 0; fj < 4; ++fj) {
                int c = col0 + wn * 64 + fj * 16 + lc;
                f32x4 v = acc[fi][fj];
                float bv = bvp[c];
                ushort4 ov = {f2bf(v[0] + bv), f2bf(v[1] + bv),
                              f2bf(v[2] + bv), f2bf(v[3] + bv)};
                *(ushort4*)&vt[((size_t)b * E + c) * 512 + t0] = ov;
            }
        }
    } else {                             // ---- z region -> q,k fused (SWAP) ----
        int bx = t - 1536;
        int row0 = bx * 128;
        const unsigned short* Ab = xn + (size_t)row0 * D;
        const unsigned short* Bb = Wt + (size_t)3072 * D;
        f32x4 acc[4][4] = {};
        gemm_core<128, 128, 2, 2, true>(Ab, Bb, D, lsA, lsB, acc, lane, wv);
#pragma unroll
        for (int fi = 0; fi < 4; ++fi) {
            int r = row0 + wm * 64 + fi * 16 + lc;
            int s = r & 511;
#pragma unroll
            for (int fj = 0; fj < 4; ++fj) {
                int cb = wn * 64 + fj * 16 + lr4;    // [0,128)
                f32x4 v = acc[fi][fj];
                f32x4 bz4 = *(const f32x4*)&bzp[cb];
                f32x4 gq4 = *(const f32x4*)&gq[(size_t)s * SD + cb];
                f32x4 bq4 = *(const f32x4*)&bq[(size_t)s * SD + cb];
                f32x4 gk4 = *(const f32x4*)&gk[(size_t)s * SD + cb];
                f32x4 bk4 = *(const f32x4*)&bk[(size_t)s * SD + cb];
                ushort4 qv, kv;
#pragma unroll
                for (int g = 0; g < 4; ++g) {
                    float zz = v[g] + bz4[g];
                    ((unsigned short*)&qv)[g] = f2bf(fmaf(zz, gq4[g], bq4[g]));
                    ((unsigned short*)&kv)[g] = f2bf(fmaf(zz, gk4[g], bk4[g]));
                }
                *(ushort4*)&q[(size_t)r * SD + cb] = qv;
                *(ushort4*)&k[(size_t)r * SD + cb] = kv;
            }
        }
    }
}

// ---- scores: a = relu^2(q@k^T) masked, BM=128 BN=64, K=128 fully prefetched -------
// Both K-tiles staged into separate buffers up front -> ONE barrier, no buffer reuse.
// grid (4, 8, B). LDS 48KB -> 3 blocks/CU >= grid 2/CU (no occupancy loss).
__global__ __launch_bounds__(256) void score_gemm(const unsigned short* __restrict__ q,
                                                  const unsigned short* __restrict__ km,
                                                  const unsigned char* __restrict__ maskb,
                                                  const int* __restrict__ flagp,
                                                  unsigned short* __restrict__ a) {
    __shared__ short lsA[2][128 * 64];
    __shared__ short lsB[2][64 * 64];
    int bx, by, bz;
    swz_bid(bx, by, bz);
    const int tid = threadIdx.x;
    const int lane = tid & 63, wv = tid >> 6;
    const int wm = wv >> 1, wn = wv & 1;     // 2x2 waves, wave tile 64x32
    const int row0 = bx * 128, col0 = by * 64;
    const unsigned short* Ab = q + (size_t)bz * S * SD + (size_t)row0 * SD;
    const unsigned short* Bb = km + (size_t)bz * S * SD + (size_t)col0 * SD;

    const unsigned short* ga[4]; int lofsA[4];
    const unsigned short* gb[2]; int lofsB[2];
#pragma unroll
    for (int i = 0; i < 4; ++i) {
        int s = wv * 4 + i;
        int r = s * 8 + (lane >> 3);
        int cl = (lane & 7) ^ (r & 7);
        ga[i] = Ab + (size_t)r * SD + cl * 8;
        lofsA[i] = s * 512;
    }
#pragma unroll
    for (int i = 0; i < 2; ++i) {
        int s = wv * 2 + i;
        int r = s * 8 + (lane >> 3);
        int cl = (lane & 7) ^ (r & 7);
        gb[i] = Bb + (size_t)r * SD + cl * 8;
        lofsB[i] = s * 512;
    }
    // stage both K-tiles (kt=0,1) into independent buffers, single barrier
#pragma unroll
    for (int i = 0; i < 4; ++i) gload16(ga[i], (void*)&lsA[0][lofsA[i]]);
#pragma unroll
    for (int i = 0; i < 2; ++i) gload16(gb[i], (void*)&lsB[0][lofsB[i]]);
#pragma unroll
    for (int i = 0; i < 4; ++i) gload16(ga[i] + 64, (void*)&lsA[1][lofsA[i]]);
#pragma unroll
    for (int i = 0; i < 2; ++i) gload16(gb[i] + 64, (void*)&lsB[1][lofsB[i]]);
    __syncthreads();

    f32x4 acc[4][2] = {};
#pragma unroll
    for (int kt = 0; kt < 2; ++kt) {
#pragma unroll
        for (int ks = 0; ks < 2; ++ks) {
            bf16x8 aF[4], bF[2];
#pragma unroll
            for (int f = 0; f < 4; ++f) {
                int ra = wm * 64 + f * 16 + (lane & 15);
                int ca = (ks * 4 + (lane >> 4)) ^ (ra & 7);
                aF[f] = *(const bf16x8*)&lsA[kt][ra * 64 + ca * 8];
            }
#pragma unroll
            for (int f = 0; f < 2; ++f) {
                int rb = wn * 32 + f * 16 + (lane & 15);
                int cb = (ks * 4 + (lane >> 4)) ^ (rb & 7);
                bF[f] = *(const bf16x8*)&lsB[kt][rb * 64 + cb * 8];
            }
#pragma unroll
            for (int fi = 0; fi < 4; ++fi)
#pragma unroll
                for (int fj = 0; fj < 2; ++fj)
                    acc[fi][fj] = __builtin_amdgcn_mfma_f32_16x16x32_bf16(
                        bF[fj], aF[fi], acc[fi][fj], 0, 0, 0);   // SWAP layout
        }
    }

    const int lr4 = (lane >> 4) * 4;
    const int lc = lane & 15;
    unsigned short* C = a + (size_t)bz * S * S;
    int flag = *flagp;
#pragma unroll
    for (int fi = 0; fi < 4; ++fi) {
        int r = row0 + wm * 64 + fi * 16 + lc;
#pragma unroll
        for (int fj = 0; fj < 2; ++fj) {
            int cb = col0 + wn * 32 + fj * 16 + lr4;
            f32x4 v = acc[fi][fj];
            ushort4 ov;
#pragma unroll
            for (int g = 0; g < 4; ++g) {
                int c = cb + g;
                int mv = flag ? (int)maskb[bz * S + c] : ((const int*)maskb)[bz * S + c];
                float vv = fmaxf(v[g], 0.0f);
                vv *= vv;
                ((unsigned short*)&ov)[g] = mv ? (unsigned short)0 : f2bf(vv);
            }
            *(ushort4*)&C[(size_t)r * S + cb] = ov;
        }
    }
}

// EPI: 4 u*acc->bf16 | 5 bias+residual->f32   (SWAP layout)
template <int EPI, int BM, int BN, int WM, int WN>
__global__ __launch_bounds__(256) void mgemm(const unsigned short* __restrict__ A,
                                             const unsigned short* __restrict__ Bt,
                                             const float* __restrict__ bias,
                                             const void* __restrict__ aux,
                                             const int* __restrict__ flagp,
                                             void* __restrict__ Cp,
                                             int N, int K,
                                             long sA, long sB, long sC, long sAux) {
    __shared__ short lsA[BM * 64];
    __shared__ short lsB[BN * 64];
    constexpr int FM = BM / WM / 16, FN = BN / WN / 16;
    int bx, by, bz;
    swz_bid(bx, by, bz);
    const int tid = threadIdx.x;
    const int lane = tid & 63, wv = tid >> 6;
    const int wm = wv / WN, wn = wv % WN;
    const int row0 = bx * BM, col0 = by * BN;

    const unsigned short* Ab = A + (size_t)bz * sA + (size_t)row0 * K;
    const unsigned short* Bb = Bt + (size_t)bz * sB + (size_t)col0 * K;

    f32x4 acc[FM][FN] = {};
    gemm_core<BM, BN, WM, WN, true>(Ab, Bb, K, lsA, lsB, acc, lane, wv);

    const int lr4 = (lane >> 4) * 4;
    const int lc = lane & 15;
#pragma unroll
    for (int fi = 0; fi < FM; ++fi) {
        int r = row0 + wm * (BM / WM) + fi * 16 + lc;
#pragma unroll
        for (int fj = 0; fj < FN; ++fj) {
            int cb = col0 + wn * (BN / WN) + fj * 16 + lr4;
            f32x4 v = acc[fi][fj];
            if constexpr (EPI == 4) {          // o = u * (a@v)
                const unsigned short* U = (const unsigned short*)aux + (size_t)bz * sAux;
                unsigned short* C = (unsigned short*)Cp + (size_t)bz * sC;
                size_t off = (size_t)r * N + cb;
                ushort4 uu = *(const ushort4*)&U[off];
                ushort4 ov = {f2bf(bf2f(uu.x) * v[0]), f2bf(bf2f(uu.y) * v[1]),
                              f2bf(bf2f(uu.z) * v[2]), f2bf(bf2f(uu.w) * v[3])};
                *(ushort4*)&C[off] = ov;
            } else {                           // EPI 5: bias + residual, f32 in-place
                float* C = (float*)Cp;
                const float* X = (const float*)aux;
                size_t off = (size_t)r * N + cb;
                f32x4 bb = *(const f32x4*)&bias[cb];
                f32x4 xx = *(const f32x4*)&X[off];
                f32x4 ov = {v[0] + bb[0] + xx[0], v[1] + bb[1] + xx[1],
                            v[2] + bb[2] + xx[2], v[3] + bb[3] + xx[3]};
                *(f32x4*)&C[off] = ov;
            }
        }
    }
}

extern "C" void kernel_launch(void* const* d_in, const int* in_sizes, int n_in,
                              void* d_out, int out_size, void* d_ws, size_t ws_size,
                              hipStream_t stream) {
    const int* tok = (const int*)d_in[0];
    const unsigned char* mask = (const unsigned char*)d_in[1];
    const float* embed = (const float*)d_in[2];
    const float* ln_g = (const float*)d_in[3];
    const float* ln_b = (const float*)d_in[4];
    const float* Wz = (const float*)d_in[5];
    const float* bz = (const float*)d_in[6];
    const float* gq = (const float*)d_in[7];
    const float* bq = (const float*)d_in[8];
    const float* gk = (const float*)d_in[9];
    const float* bk = (const float*)d_in[10];
    const float* Wu = (const float*)d_in[11];
    const float* bu = (const float*)d_in[12];
    const float* Wv = (const float*)d_in[13];
    const float* bv = (const float*)d_in[14];
    const float* Wo = (const float*)d_in[15];
    const float* bo = (const float*)d_in[16];
    const float* fin_g = (const float*)d_in[17];
    const float* fin_b = (const float*)d_in[18];

    char* wsb = (char*)d_ws;
    size_t off = 0;
    auto alloc = [&](size_t nbytes) {
        void* p = wsb + off;
        off = (off + nbytes + 255) & ~(size_t)255;
        return p;
    };
    int* flag = (int*)alloc(256);
    float* x = (float*)alloc((size_t)B * S * D * 4);
    unsigned short* xn = (unsigned short*)alloc((size_t)B * S * D * 2);
    unsigned short* q = (unsigned short*)alloc((size_t)B * S * SD * 2);
    unsigned short* k = (unsigned short*)alloc((size_t)B * S * SD * 2);
    unsigned short* u = (unsigned short*)alloc((size_t)B * S * E * 2);
    unsigned short* vt = (unsigned short*)alloc((size_t)B * E * S * 2);
    unsigned short* o = (unsigned short*)alloc((size_t)B * S * E * 2);
    unsigned short* a = (unsigned short*)alloc((size_t)B * S * S * 2);
    unsigned short* Wuvzt = (unsigned short*)alloc((size_t)L * 3200 * D * 2);
    unsigned short* Wot = (unsigned short*)alloc((size_t)L * D * E * 2);

    constexpr long WUVZ = 3200L * D;   // per-layer stride of concat weight [u|v|z]

    embed_kernel<<<(B * S * D) / 256, 256, 0, stream>>>(tok, embed, x, mask, flag);
    tcast_all<<<dim3(2368, 1, L), 256, 0, stream>>>(Wu, Wv, Wz, Wo, Wuvzt, Wot);

    for (int l = 0; l < L; ++l) {
        ln_kernel<true><<<B * S / 4, 256, 0, stream>>>(x, ln_g + l * D, ln_b + l * D, xn);
        uvz_gemm<<<dim3(1600), 256, 0, stream>>>(
            xn, Wuvzt + (size_t)l * WUVZ, bu + l * E, bv + l * E, bz + l * SD,
            gq + (size_t)l * S * SD, bq + (size_t)l * S * SD,
            gk + (size_t)l * S * SD, bk + (size_t)l * S * SD, u, vt, q, k);
        score_gemm<<<dim3(4, 8, B), 256, 0, stream>>>(q, k, mask, flag, a);
        mgemm<4, 128, 128, 2, 2><<<dim3(4, 12, B), 256, 0, stream>>>(
            a, vt, nullptr, u, nullptr, o, E, S,
            (long)S * S, (long)E * S, (long)S * E, (long)S * E);
        mgemm<5, 128, 64, 2, 2><<<dim3(64, 8), 256, 0, stream>>>(
            o, Wot + (size_t)l * D * E, bo + l * D, x, nullptr, x, D, E, 0, 0, 0, 0);
    }
    ln_kernel<false><<<B * S / 4, 256, 0, stream>>>(x, fin_g, fin_b, (float*)d_out);
}

// Round 12
// 711.841 us; speedup vs baseline: 1.1444x; 1.1138x over previous
//
#include <hip/hip_runtime.h>
#include <hip/hip_bf16.h>
#include <stdint.h>

constexpr int L = 6, B = 16, S = 512, D = 512, SD = 128, E = 1536;

using bf16x8 = __attribute__((ext_vector_type(8))) short;
using f32x4  = __attribute__((ext_vector_type(4))) float;

typedef __attribute__((address_space(1))) void gvoid;
typedef __attribute__((address_space(3))) void lvoid;

__device__ __forceinline__ unsigned short f2bf(float f) {
    __hip_bfloat16 h = __float2bfloat16(f);
    return __builtin_bit_cast(unsigned short, h);
}
__device__ __forceinline__ float bf2f(unsigned short u) {
    unsigned int v = ((unsigned int)u) << 16;
    return __builtin_bit_cast(float, v);
}
__device__ __forceinline__ void gload16(const void* g, void* l) {
    __builtin_amdgcn_global_load_lds((gvoid*)g, (lvoid*)l, 16, 0, 0);
}

// bijective XCD-chunk swizzle (requires total blocks % 8 == 0).
__device__ __forceinline__ void swz_bid(int& bx, int& by, int& bz) {
    int gx = gridDim.x, gy = gridDim.y, gz = gridDim.z;
    int n = gx * gy * gz;
    int id = blockIdx.x + gx * (blockIdx.y + gy * blockIdx.z);
    int id2 = (id & 7) * (n >> 3) + (id >> 3);
    by = id2 % gy;
    int t = id2 / gy;
    bx = t % gx;
    bz = t / gx;
}

// ---------------- embedding + positional encoding (+ mask-layout detect, block 0) --
__global__ void embed_kernel(const int* __restrict__ tok, const float* __restrict__ embed,
                             float* __restrict__ x,
                             const unsigned char* __restrict__ m, int* flag) {
    if (blockIdx.x == 0) {
        if (threadIdx.x == 0) *flag = 0;
        __syncthreads();
        int any = 0;
        for (int i = threadIdx.x; i < B * S; i += blockDim.x)
            if ((i & 3) != 0 && m[i] != 0) any = 1;
        if (any) atomicOr(flag, 1);
    }
    int idx = blockIdx.x * blockDim.x + threadIdx.x;      // over B*S*D
    int d = idx & (D - 1);
    int bs = idx >> 9;                                    // D = 512 = 2^9
    int s = bs & (S - 1);
    float e = embed[(size_t)tok[bs] * D + d] * 22.62741699796952f;  // sqrt(512)
    float expo = (float)(d >> 1) * (1.0f / 256.0f);
    float ang = (float)s * expf(expo * -9.210340371976184f);
    float pe = (d & 1) ? cosf(ang) : sinf(ang);
    x[idx] = e + pe;
}

// ---- fused weight transpose+cast, all 4 weights, one launch. grid (2368, 1, L) ----
// tiles: [0,768) Wu 512x1536 | [768,1536) Wv | [1536,1600) Wz 512x128 | [1600,2368) Wo 1536x512
__global__ __launch_bounds__(256) void tcast_all(const float* __restrict__ Wu,
                                                 const float* __restrict__ Wv,
                                                 const float* __restrict__ Wz,
                                                 const float* __restrict__ Wo,
                                                 unsigned short* __restrict__ Wuvzt,
                                                 unsigned short* __restrict__ Wot) {
    constexpr long WUVZ = 3200L * 512;
    int l = blockIdx.z;
    int t = blockIdx.x;
    const float* src; unsigned short* dst; int K, N, r;
    if (t < 768)       { r = t;        src = Wu + (size_t)l * 512 * 1536; dst = Wuvzt + (size_t)l * WUVZ;               K = 512;  N = 1536; }
    else if (t < 1536) { r = t - 768;  src = Wv + (size_t)l * 512 * 1536; dst = Wuvzt + (size_t)l * WUVZ + 1536L * 512; K = 512;  N = 1536; }
    else if (t < 1600) { r = t - 1536; src = Wz + (size_t)l * 512 * 128;  dst = Wuvzt + (size_t)l * WUVZ + 3072L * 512; K = 512;  N = 128;  }
    else               { r = t - 1600; src = Wo + (size_t)l * 1536 * 512; dst = Wot + (size_t)l * 1536 * 512;           K = 1536; N = 512;  }
    int kx = K / 32;
    int k0 = (r % kx) * 32, n0 = (r / kx) * 32;
    __shared__ float tb[32][33];
    int tx = threadIdx.x & 31, ty = threadIdx.x >> 5;     // 32 x 8
#pragma unroll
    for (int i = 0; i < 4; ++i)
        tb[ty + i * 8][tx] = src[(size_t)(k0 + ty + i * 8) * N + n0 + tx];
    __syncthreads();
#pragma unroll
    for (int i = 0; i < 4; ++i)
        dst[(size_t)(n0 + ty + i * 8) * K + k0 + tx] = f2bf(tb[tx][ty + i * 8]);
}

// ---------------- layernorm: 4 rows/block, one wave per row of D=512 ----------------
template <bool BF>
__global__ __launch_bounds__(256) void ln_kernel(const float* __restrict__ x,
                                                 const float* __restrict__ g,
                                                 const float* __restrict__ b,
                                                 void* __restrict__ yp) {
    int row = blockIdx.x * 4 + (threadIdx.x >> 6);
    int lane = threadIdx.x & 63;
    const float* xr = x + (size_t)row * D;
    float4 v0 = *(const float4*)(xr + lane * 4);
    float4 v1 = *(const float4*)(xr + 256 + lane * 4);
    float sum = v0.x + v0.y + v0.z + v0.w + v1.x + v1.y + v1.z + v1.w;
#pragma unroll
    for (int o = 1; o < 64; o <<= 1) sum += __shfl_xor(sum, o);
    float m = sum * (1.0f / D);
    float d0 = v0.x - m, d1 = v0.y - m, d2 = v0.z - m, d3 = v0.w - m;
    float e0 = v1.x - m, e1 = v1.y - m, e2 = v1.z - m, e3 = v1.w - m;
    float sq = d0 * d0 + d1 * d1 + d2 * d2 + d3 * d3 + e0 * e0 + e1 * e1 + e2 * e2 + e3 * e3;
#pragma unroll
    for (int o = 1; o < 64; o <<= 1) sq += __shfl_xor(sq, o);
    float inv = rsqrtf(sq * (1.0f / D) + 1e-5f);
    int c0 = lane * 4, c1 = 256 + lane * 4;
    float4 g0 = *(const float4*)(g + c0), g1 = *(const float4*)(g + c1);
    float4 b0 = *(const float4*)(b + c0), b1 = *(const float4*)(b + c1);
    float o0 = d0 * inv * g0.x + b0.x, o1 = d1 * inv * g0.y + b0.y;
    float o2 = d2 * inv * g0.z + b0.z, o3 = d3 * inv * g0.w + b0.w;
    float o4 = e0 * inv * g1.x + b1.x, o5 = e1 * inv * g1.y + b1.y;
    float o6 = e2 * inv * g1.z + b1.z, o7 = e3 * inv * g1.w + b1.w;
    if constexpr (BF) {
        unsigned short* yr = (unsigned short*)yp + (size_t)row * D;
        ushort4 p0 = {f2bf(o0), f2bf(o1), f2bf(o2), f2bf(o3)};
        ushort4 p1 = {f2bf(o4), f2bf(o5), f2bf(o6), f2bf(o7)};
        *(ushort4*)(yr + c0) = p0;
        *(ushort4*)(yr + c1) = p1;
    } else {
        float* yr = (float*)yp + (size_t)row * D;
        float4 p0 = {o0, o1, o2, o3}, p1 = {o4, o5, o6, o7};
        *(float4*)(yr + c0) = p0;
        *(float4*)(yr + c1) = p1;
    }
}

// ---------------- MFMA GEMM core: tile BM x BN, BK=64, WM x WN waves --------------
// (R6 text — verified fastest codegen.) LDS [rows][64] bf16, chunk-XOR swizzle
// phys_chunk = log_chunk ^ (row&7). Staging via global_load_lds(16B), pre-swizzled
// per-lane global source. SWAP=true: mfma(bF,aF) -> lane regs walk N => coalesced C.
template <int BM, int BN, int WM, int WN, bool SWAP>
__device__ __forceinline__ void gemm_core(const unsigned short* __restrict__ Ab,
                                          const unsigned short* __restrict__ Bb,
                                          int K, short* lsA, short* lsB,
                                          f32x4 (&acc)[BM / WM / 16][BN / WN / 16],
                                          int lane, int wv) {
    constexpr int NW = WM * WN;
    constexpr int NA = BM / 8 / NW, NB = BN / 8 / NW;   // 1KB segs per wave
    constexpr int WTM = BM / WM, WTN = BN / WN;
    constexpr int FM = WTM / 16, FN = WTN / 16;
    const int wm = wv / WN, wn = wv % WN;
    const unsigned short* ga[NA]; int lofsA[NA];
    const unsigned short* gb[NB]; int lofsB[NB];
#pragma unroll
    for (int i = 0; i < NA; ++i) {
        int s = wv * NA + i;
        int r = s * 8 + (lane >> 3);
        int cl = (lane & 7) ^ (r & 7);
        ga[i] = Ab + (size_t)r * K + cl * 8;
        lofsA[i] = s * 512;
    }
#pragma unroll
    for (int i = 0; i < NB; ++i) {
        int s = wv * NB + i;
        int r = s * 8 + (lane >> 3);
        int cl = (lane & 7) ^ (r & 7);
        gb[i] = Bb + (size_t)r * K + cl * 8;
        lofsB[i] = s * 512;
    }
    const int nkt = K >> 6;
    for (int kt = 0; kt < nkt; ++kt) {
        if (kt) __syncthreads();
#pragma unroll
        for (int i = 0; i < NA; ++i) gload16(ga[i] + kt * 64, (void*)&lsA[lofsA[i]]);
#pragma unroll
        for (int i = 0; i < NB; ++i) gload16(gb[i] + kt * 64, (void*)&lsB[lofsB[i]]);
        __syncthreads();
#pragma unroll
        for (int ks = 0; ks < 2; ++ks) {
            bf16x8 aF[FM], bF[FN];
#pragma unroll
            for (int f = 0; f < FM; ++f) {
                int ra = wm * WTM + f * 16 + (lane & 15);
                int ca = (ks * 4 + (lane >> 4)) ^ (ra & 7);
                aF[f] = *(const bf16x8*)&lsA[ra * 64 + ca * 8];
            }
#pragma unroll
            for (int f = 0; f < FN; ++f) {
                int rb = wn * WTN + f * 16 + (lane & 15);
                int cb = (ks * 4 + (lane >> 4)) ^ (rb & 7);
                bF[f] = *(const bf16x8*)&lsB[rb * 64 + cb * 8];
            }
#pragma unroll
            for (int fi = 0; fi < FM; ++fi)
#pragma unroll
                for (int fj = 0; fj < FN; ++fj) {
                    if constexpr (SWAP)
                        acc[fi][fj] = __builtin_amdgcn_mfma_f32_16x16x32_bf16(
                            bF[fj], aF[fi], acc[fi][fj], 0, 0, 0);
                    else
                        acc[fi][fj] = __builtin_amdgcn_mfma_f32_16x16x32_bf16(
                            aF[fi], bF[fj], acc[fi][fj], 0, 0, 0);
                }
        }
    }
}

// ---------------- fused u|v GEMM over xn(8192x512): grid (64, 12, 2) ----------------
// bz=0: u = xn@Wu+bu -> bf16 row-major (SWAP). bz=1: v^T[b][c][t] (NOSWAP).
__global__ __launch_bounds__(256) void uv_gemm(const unsigned short* __restrict__ xn,
                                               const unsigned short* __restrict__ Wuvt,
                                               const float* __restrict__ bu,
                                               const float* __restrict__ bvp,
                                               unsigned short* __restrict__ u,
                                               unsigned short* __restrict__ vt) {
    __shared__ short lsA[128 * 64];
    __shared__ short lsB[128 * 64];
    int bx, by, bz;
    swz_bid(bx, by, bz);
    const int tid = threadIdx.x;
    const int lane = tid & 63, wv = tid >> 6;
    const int wm = wv >> 1, wn = wv & 1;
    const int row0 = bx * 128, col0 = by * 128;
    const unsigned short* Ab = xn + (size_t)row0 * D;
    const unsigned short* Bb = Wuvt + ((size_t)bz * E + col0) * D;

    const int lr4 = (lane >> 4) * 4;
    const int lc = lane & 15;
    if (bz == 0) {
        f32x4 acc[4][4] = {};
        gemm_core<128, 128, 2, 2, true>(Ab, Bb, D, lsA, lsB, acc, lane, wv);
#pragma unroll
        for (int fi = 0; fi < 4; ++fi) {
            int r = row0 + wm * 64 + fi * 16 + lc;
#pragma unroll
            for (int fj = 0; fj < 4; ++fj) {
                int cb = col0 + wn * 64 + fj * 16 + lr4;
                f32x4 v = acc[fi][fj];
                f32x4 bv = *(const f32x4*)&bu[cb];
                ushort4 ov = {f2bf(v[0] + bv[0]), f2bf(v[1] + bv[1]),
                              f2bf(v[2] + bv[2]), f2bf(v[3] + bv[3])};
                *(ushort4*)&u[(size_t)r * E + cb] = ov;
            }
        }
    } else {
        f32x4 acc[4][4] = {};
        gemm_core<128, 128, 2, 2, false>(Ab, Bb, D, lsA, lsB, acc, lane, wv);
#pragma unroll
        for (int fi = 0; fi < 4; ++fi) {
            int rb = row0 + wm * 64 + fi * 16 + lr4;
            int b = rb >> 9, t0 = rb & 511;
#pragma unroll
            for (int fj = 0; fj < 4; ++fj) {
                int c = col0 + wn * 64 + fj * 16 + lc;
                f32x4 v = acc[fi][fj];
                float bv = bvp[c];
                ushort4 ov = {f2bf(v[0] + bv), f2bf(v[1] + bv),
                              f2bf(v[2] + bv), f2bf(v[3] + bv)};
                *(ushort4*)&vt[((size_t)b * E + c) * 512 + t0] = ov;
            }
        }
    }
}

// ------ z GEMM fused with q/k elementwise (SWAP), 64x64 tiles: grid (128, 2) -------
__global__ __launch_bounds__(256) void zqk_gemm(const unsigned short* __restrict__ xn,
                                                const unsigned short* __restrict__ Bt,
                                                const float* __restrict__ bias,
                                                const float* __restrict__ gq,
                                                const float* __restrict__ bq,
                                                const float* __restrict__ gk,
                                                const float* __restrict__ bk,
                                                unsigned short* __restrict__ q,
                                                unsigned short* __restrict__ k) {
    __shared__ short lsA[64 * 64];
    __shared__ short lsB[64 * 64];
    int bx, by, bz;
    swz_bid(bx, by, bz);
    const int tid = threadIdx.x;
    const int lane = tid & 63, wv = tid >> 6;
    const int wm = wv >> 1, wn = wv & 1;
    const int row0 = bx * 64, col0 = by * 64;
    const unsigned short* Ab = xn + (size_t)row0 * D;
    const unsigned short* Bb = Bt + (size_t)col0 * D;

    f32x4 acc[2][2] = {};
    gemm_core<64, 64, 2, 2, true>(Ab, Bb, D, lsA, lsB, acc, lane, wv);

    const int lr4 = (lane >> 4) * 4;
    const int lc = lane & 15;
#pragma unroll
    for (int fi = 0; fi < 2; ++fi) {
        int r = row0 + wm * 32 + fi * 16 + lc;
        int s = r & 511;
#pragma unroll
        for (int fj = 0; fj < 2; ++fj) {
            int cb = col0 + wn * 32 + fj * 16 + lr4;
            f32x4 v = acc[fi][fj];
            f32x4 bz4 = *(const f32x4*)&bias[cb];
            f32x4 gq4 = *(const f32x4*)&gq[(size_t)s * SD + cb];
            f32x4 bq4 = *(const f32x4*)&bq[(size_t)s * SD + cb];
            f32x4 gk4 = *(const f32x4*)&gk[(size_t)s * SD + cb];
            f32x4 bk4 = *(const f32x4*)&bk[(size_t)s * SD + cb];
            ushort4 qv, kv;
#pragma unroll
            for (int g = 0; g < 4; ++g) {
                float zz = v[g] + bz4[g];
                ((unsigned short*)&qv)[g] = f2bf(fmaf(zz, gq4[g], bq4[g]));
                ((unsigned short*)&kv)[g] = f2bf(fmaf(zz, gk4[g], bk4[g]));
            }
            *(ushort4*)&q[(size_t)r * SD + cb] = qv;
            *(ushort4*)&k[(size_t)r * SD + cb] = kv;
        }
    }
}

// ---- scores: a = relu^2(q@k^T) masked, BM=128 BN=64, K=128 fully prefetched -------
// Both K-tiles staged into separate buffers up front -> ONE barrier, no buffer reuse.
// grid (4, 8, B). LDS 48KB -> 3 blocks/CU >= grid 2/CU (no occupancy loss).
__global__ __launch_bounds__(256) void score_gemm(const unsigned short* __restrict__ q,
                                                  const unsigned short* __restrict__ km,
                                                  const unsigned char* __restrict__ maskb,
                                                  const int* __restrict__ flagp,
                                                  unsigned short* __restrict__ a) {
    __shared__ short lsA[2][128 * 64];
    __shared__ short lsB[2][64 * 64];
    int bx, by, bz;
    swz_bid(bx, by, bz);
    const int tid = threadIdx.x;
    const int lane = tid & 63, wv = tid >> 6;
    const int wm = wv >> 1, wn = wv & 1;     // 2x2 waves, wave tile 64x32
    const int row0 = bx * 128, col0 = by * 64;
    const unsigned short* Ab = q + (size_t)bz * S * SD + (size_t)row0 * SD;
    const unsigned short* Bb = km + (size_t)bz * S * SD + (size_t)col0 * SD;

    const unsigned short* ga[4]; int lofsA[4];
    const unsigned short* gb[2]; int lofsB[2];
#pragma unroll
    for (int i = 0; i < 4; ++i) {
        int s = wv * 4 + i;
        int r = s * 8 + (lane >> 3);
        int cl = (lane & 7) ^ (r & 7);
        ga[i] = Ab + (size_t)r * SD + cl * 8;
        lofsA[i] = s * 512;
    }
#pragma unroll
    for (int i = 0; i < 2; ++i) {
        int s = wv * 2 + i;
        int r = s * 8 + (lane >> 3);
        int cl = (lane & 7) ^ (r & 7);
        gb[i] = Bb + (size_t)r * SD + cl * 8;
        lofsB[i] = s * 512;
    }
    // stage both K-tiles (kt=0,1) into independent buffers, single barrier
#pragma unroll
    for (int i = 0; i < 4; ++i) gload16(ga[i], (void*)&lsA[0][lofsA[i]]);
#pragma unroll
    for (int i = 0; i < 2; ++i) gload16(gb[i], (void*)&lsB[0][lofsB[i]]);
#pragma unroll
    for (int i = 0; i < 4; ++i) gload16(ga[i] + 64, (void*)&lsA[1][lofsA[i]]);
#pragma unroll
    for (int i = 0; i < 2; ++i) gload16(gb[i] + 64, (void*)&lsB[1][lofsB[i]]);
    __syncthreads();

    f32x4 acc[4][2] = {};
#pragma unroll
    for (int kt = 0; kt < 2; ++kt) {
#pragma unroll
        for (int ks = 0; ks < 2; ++ks) {
            bf16x8 aF[4], bF[2];
#pragma unroll
            for (int f = 0; f < 4; ++f) {
                int ra = wm * 64 + f * 16 + (lane & 15);
                int ca = (ks * 4 + (lane >> 4)) ^ (ra & 7);
                aF[f] = *(const bf16x8*)&lsA[kt][ra * 64 + ca * 8];
            }
#pragma unroll
            for (int f = 0; f < 2; ++f) {
                int rb = wn * 32 + f * 16 + (lane & 15);
                int cb = (ks * 4 + (lane >> 4)) ^ (rb & 7);
                bF[f] = *(const bf16x8*)&lsB[kt][rb * 64 + cb * 8];
            }
#pragma unroll
            for (int fi = 0; fi < 4; ++fi)
#pragma unroll
                for (int fj = 0; fj < 2; ++fj)
                    acc[fi][fj] = __builtin_amdgcn_mfma_f32_16x16x32_bf16(
                        bF[fj], aF[fi], acc[fi][fj], 0, 0, 0);   // SWAP layout
        }
    }

    const int lr4 = (lane >> 4) * 4;
    const int lc = lane & 15;
    unsigned short* C = a + (size_t)bz * S * S;
    int flag = *flagp;
#pragma unroll
    for (int fi = 0; fi < 4; ++fi) {
        int r = row0 + wm * 64 + fi * 16 + lc;
#pragma unroll
        for (int fj = 0; fj < 2; ++fj) {
            int cb = col0 + wn * 32 + fj * 16 + lr4;
            f32x4 v = acc[fi][fj];
            ushort4 ov;
#pragma unroll
            for (int g = 0; g < 4; ++g) {
                int c = cb + g;
                int mv = flag ? (int)maskb[bz * S + c] : ((const int*)maskb)[bz * S + c];
                float vv = fmaxf(v[g], 0.0f);
                vv *= vv;
                ((unsigned short*)&ov)[g] = mv ? (unsigned short)0 : f2bf(vv);
            }
            *(ushort4*)&C[(size_t)r * S + cb] = ov;
        }
    }
}

// EPI: 4 u*acc->bf16 | 5 bias+residual->f32   (SWAP layout)
template <int EPI, int BM, int BN, int WM, int WN>
__global__ __launch_bounds__(256) void mgemm(const unsigned short* __restrict__ A,
                                             const unsigned short* __restrict__ Bt,
                                             const float* __restrict__ bias,
                                             const void* __restrict__ aux,
                                             const int* __restrict__ flagp,
                                             void* __restrict__ Cp,
                                             int N, int K,
                                             long sA, long sB, long sC, long sAux) {
    __shared__ short lsA[BM * 64];
    __shared__ short lsB[BN * 64];
    constexpr int FM = BM / WM / 16, FN = BN / WN / 16;
    int bx, by, bz;
    swz_bid(bx, by, bz);
    const int tid = threadIdx.x;
    const int lane = tid & 63, wv = tid >> 6;
    const int wm = wv / WN, wn = wv % WN;
    const int row0 = bx * BM, col0 = by * BN;

    const unsigned short* Ab = A + (size_t)bz * sA + (size_t)row0 * K;
    const unsigned short* Bb = Bt + (size_t)bz * sB + (size_t)col0 * K;

    f32x4 acc[FM][FN] = {};
    gemm_core<BM, BN, WM, WN, true>(Ab, Bb, K, lsA, lsB, acc, lane, wv);

    const int lr4 = (lane >> 4) * 4;
    const int lc = lane & 15;
#pragma unroll
    for (int fi = 0; fi < FM; ++fi) {
        int r = row0 + wm * (BM / WM) + fi * 16 + lc;
#pragma unroll
        for (int fj = 0; fj < FN; ++fj) {
            int cb = col0 + wn * (BN / WN) + fj * 16 + lr4;
            f32x4 v = acc[fi][fj];
            if constexpr (EPI == 4) {          // o = u * (a@v)
                const unsigned short* U = (const unsigned short*)aux + (size_t)bz * sAux;
                unsigned short* C = (unsigned short*)Cp + (size_t)bz * sC;
                size_t off = (size_t)r * N + cb;
                ushort4 uu = *(const ushort4*)&U[off];
                ushort4 ov = {f2bf(bf2f(uu.x) * v[0]), f2bf(bf2f(uu.y) * v[1]),
                              f2bf(bf2f(uu.z) * v[2]), f2bf(bf2f(uu.w) * v[3])};
                *(ushort4*)&C[off] = ov;
            } else {                           // EPI 5: bias + residual, f32 in-place
                float* C = (float*)Cp;
                const float* X = (const float*)aux;
                size_t off = (size_t)r * N + cb;
                f32x4 bb = *(const f32x4*)&bias[cb];
                f32x4 xx = *(const f32x4*)&X[off];
                f32x4 ov = {v[0] + bb[0] + xx[0], v[1] + bb[1] + xx[1],
                            v[2] + bb[2] + xx[2], v[3] + bb[3] + xx[3]};
                *(f32x4*)&C[off] = ov;
            }
        }
    }
}

extern "C" void kernel_launch(void* const* d_in, const int* in_sizes, int n_in,
                              void* d_out, int out_size, void* d_ws, size_t ws_size,
                              hipStream_t stream) {
    const int* tok = (const int*)d_in[0];
    const unsigned char* mask = (const unsigned char*)d_in[1];
    const float* embed = (const float*)d_in[2];
    const float* ln_g = (const float*)d_in[3];
    const float* ln_b = (const float*)d_in[4];
    const float* Wz = (const float*)d_in[5];
    const float* bz = (const float*)d_in[6];
    const float* gq = (const float*)d_in[7];
    const float* bq = (const float*)d_in[8];
    const float* gk = (const float*)d_in[9];
    const float* bk = (const float*)d_in[10];
    const float* Wu = (const float*)d_in[11];
    const float* bu = (const float*)d_in[12];
    const float* Wv = (const float*)d_in[13];
    const float* bv = (const float*)d_in[14];
    const float* Wo = (const float*)d_in[15];
    const float* bo = (const float*)d_in[16];
    const float* fin_g = (const float*)d_in[17];
    const float* fin_b = (const float*)d_in[18];

    char* wsb = (char*)d_ws;
    size_t off = 0;
    auto alloc = [&](size_t nbytes) {
        void* p = wsb + off;
        off = (off + nbytes + 255) & ~(size_t)255;
        return p;
    };
    int* flag = (int*)alloc(256);
    float* x = (float*)alloc((size_t)B * S * D * 4);
    unsigned short* xn = (unsigned short*)alloc((size_t)B * S * D * 2);
    unsigned short* q = (unsigned short*)alloc((size_t)B * S * SD * 2);
    unsigned short* k = (unsigned short*)alloc((size_t)B * S * SD * 2);
    unsigned short* u = (unsigned short*)alloc((size_t)B * S * E * 2);
    unsigned short* vt = (unsigned short*)alloc((size_t)B * E * S * 2);
    unsigned short* o = (unsigned short*)alloc((size_t)B * S * E * 2);
    unsigned short* a = (unsigned short*)alloc((size_t)B * S * S * 2);
    unsigned short* Wuvzt = (unsigned short*)alloc((size_t)L * 3200 * D * 2);
    unsigned short* Wot = (unsigned short*)alloc((size_t)L * D * E * 2);

    constexpr long WUVZ = 3200L * D;   // per-layer stride of concat weight [u|v|z]

    embed_kernel<<<(B * S * D) / 256, 256, 0, stream>>>(tok, embed, x, mask, flag);
    tcast_all<<<dim3(2368, 1, L), 256, 0, stream>>>(Wu, Wv, Wz, Wo, Wuvzt, Wot);

    for (int l = 0; l < L; ++l) {
        ln_kernel<true><<<B * S / 4, 256, 0, stream>>>(x, ln_g + l * D, ln_b + l * D, xn);
        uv_gemm<<<dim3(64, 12, 2), 256, 0, stream>>>(
            xn, Wuvzt + (size_t)l * WUVZ, bu + l * E, bv + l * E, u, vt);
        zqk_gemm<<<dim3(128, 2), 256, 0, stream>>>(
            xn, Wuvzt + (size_t)l * WUVZ + 3072L * D, bz + l * SD,
            gq + (size_t)l * S * SD, bq + (size_t)l * S * SD,
            gk + (size_t)l * S * SD, bk + (size_t)l * S * SD, q, k);
        score_gemm<<<dim3(4, 8, B), 256, 0, stream>>>(q, k, mask, flag, a);
        mgemm<4, 128, 128, 2, 2><<<dim3(4, 12, B), 256, 0, stream>>>(
            a, vt, nullptr, u, nullptr, o, E, S,
            (long)S * S, (long)E * S, (long)S * E, (long)S * E);
        mgemm<5, 128, 64, 2, 2><<<dim3(64, 8), 256, 0, stream>>>(
            o, Wot + (size_t)l * D * E, bo + l * D, x, nullptr, x, D, E, 0, 0, 0, 0);
    }
    ln_kernel<false><<<B * S / 4, 256, 0, stream>>>(x, fin_g, fin_b, (float*)d_out);
}